// Round 5
// baseline (4084.714 us; speedup 1.0000x reference)
//
#include <hip/hip_runtime.h>
#include <stdint.h>

// Problem dims (fixed by the reference)
#define TT 512
#define BB 256
#define DD 256
#define HH 512

// 16 batch-groups x 16 H-slices = 256 WGs, 1 per CU (147KB LDS pins this).
// Groups formed dynamically from HW_REG_XCC_ID (HW-verified, learn_hip m09) so
// all 16 WGs of a group share one XCD L2. h-exchange: FAST path = plain store
// + sc0 load through the shared L2; MIRROR path = sc0sc1 (LLC, proven r2/r3)
// as bounded-timeout fallback -> deadlock-impossible even if grouping fails.
#define WSL 32
#define NGROUP 16
#define KS_X 8
#define KS_H 16
#define KS_TOT 24
#define NBLK 144
#define TAG_OFF 7        // tags in [7,518]: never 0x0000 / 0xAAAA / 0xFFFF
#define FAST_TRIES 40

typedef __attribute__((ext_vector_type(8))) short short8;
typedef __attribute__((ext_vector_type(4))) float floatx4;
typedef __attribute__((ext_vector_type(4))) unsigned int uintx4;

__device__ __forceinline__ short f2bf(float v) {
    union { float f; uint32_t u; } x; x.f = v;
    uint32_t r = (x.u + 0x7fffu + ((x.u >> 16) & 1u)) >> 16;   // RNE
    return (short)r;
}
__device__ __forceinline__ float bf2f_hi(unsigned int s) {     // bf16 in HIGH half
    union { uint32_t u; float f; } x; x.u = s & 0xffff0000u;
    return x.f;
}
__device__ __forceinline__ float sigm(float v) { return 1.0f / (1.0f + __expf(-v)); }

// Per-launch: zero the 8 per-XCD rank counters (device-scope stores so the
// ranking RMWs, which resolve at the same coherence point, see them).
__global__ __launch_bounds__(64)
void clear_ws(unsigned int* xcnt) {
    if (threadIdx.x < 8)
        __hip_atomic_store(&xcnt[threadIdx.x], 0u, __ATOMIC_RELAXED,
                           __HIP_MEMORY_SCOPE_AGENT);
}

__global__ __launch_bounds__(128, 1)
void gru_persistent(const float* __restrict__ x,
                    const float* __restrict__ h0,
                    const int*   __restrict__ ep,
                    const float* __restrict__ w_ih,
                    const float* __restrict__ w_hh,
                    const float* __restrict__ b_ih,
                    const float* __restrict__ b_hh,
                    float* __restrict__ out,
                    unsigned int* __restrict__ fx,     // fast ping-pong (XCD L2)
                    unsigned int* __restrict__ mx,     // mirror ping-pong (LLC)
                    unsigned int* __restrict__ xcnt) {
    __shared__ short ldsw[NBLK * 512];
    __shared__ int s_rank;

    const int tid  = threadIdx.x;
    const int lane = tid & 63;
    const int w    = tid >> 6;

    // ---- dynamic same-XCD group formation ----
    // grid=256, 147KB LDS -> 1 WG/CU -> exactly 32 WGs per XCD.
    if (tid == 0) {
        unsigned int xcc;
        asm volatile("s_getreg_b32 %0, hwreg(HW_REG_XCC_ID)" : "=s"(xcc));
        unsigned int r = __hip_atomic_fetch_add(&xcnt[xcc & 7], 1u,
                                                __ATOMIC_RELAXED, __HIP_MEMORY_SCOPE_AGENT);
        s_rank = (int)(((xcc & 7) * 32 + r) & 255);
    }
    __syncthreads();
    const int rk = s_rank;
    const int bg = rk >> 4;               // batch group 0..15 (same-XCD if XCC_ID sane)
    const int sl = rk & 15;               // H slice 0..15

    // ---- one-time: load + convert + swizzle weights into LDS ----
    for (int u = tid; u < NBLK * 64; u += 128) {
        int blk = u >> 6;
        int l   = u & 63;
        int ww  = blk / 72;
        int rem = blk % 72;
        int g   = rem / 24;
        int ks  = rem % 24;
        int row = sl * WSL + ww * 16 + (l & 15) + g * HH;
        int k0  = ks * 32 + ((l >> 4) * 8);
        const float* src = (k0 < DD) ? (w_ih + (size_t)row * DD + k0)
                                     : (w_hh + (size_t)row * HH + (k0 - DD));
        short8 v;
        #pragma unroll
        for (int j = 0; j < 8; j++) v[j] = f2bf(src[j]);
        *(short8*)&ldsw[(size_t)blk * 512 + l * 8] = v;
    }
    __syncthreads();

    const int cl   = lane & 15;
    const int col  = sl * WSL + w * 16 + cl;
    const int am   = bg * 16 + cl;
    const int rbase = (lane >> 4) * 4;
    const int k0a  = (lane >> 4) * 8;
    const float br0 = b_ih[col] + b_hh[col];
    const float bz0 = b_ih[col + HH] + b_hh[col + HH];
    const float bin = b_ih[col + 2 * HH];
    const float bhn = b_hh[col + 2 * HH];

    for (int t = 0; t < TT; t++) {
        floatx4 accI[3], accH[3];
        #pragma unroll
        for (int g = 0; g < 3; g++) {
            accI[g] = (floatx4){0.f, 0.f, 0.f, 0.f};
            accH[g] = (floatx4){0.f, 0.f, 0.f, 0.f};
        }

        // ---- x-side GEMM first (independent of h) ----
        const float* xrow = x + ((size_t)t * BB + am) * DD;
        #pragma unroll
        for (int ks = 0; ks < KS_X; ks++) {
            int k0 = ks * 32 + k0a;
            floatx4 f0 = *(const floatx4*)(xrow + k0);
            floatx4 f1 = *(const floatx4*)(xrow + k0 + 4);
            union { uintx4 u; short8 s; } cv;
            asm("v_cvt_pk_bf16_f32 %0, %1, %2" : "=v"(cv.u[0]) : "v"(f0[0]), "v"(f0[1]));
            asm("v_cvt_pk_bf16_f32 %0, %1, %2" : "=v"(cv.u[1]) : "v"(f0[2]), "v"(f0[3]));
            asm("v_cvt_pk_bf16_f32 %0, %1, %2" : "=v"(cv.u[2]) : "v"(f1[0]), "v"(f1[1]));
            asm("v_cvt_pk_bf16_f32 %0, %1, %2" : "=v"(cv.u[3]) : "v"(f1[2]), "v"(f1[3]));
            const short8 av = cv.s;
            #pragma unroll
            for (int g = 0; g < 3; g++) {
                short8 bf = *(const short8*)&ldsw[(size_t)((w * 3 + g) * KS_TOT + ks) * 512 + lane * 8];
                accI[g] = __builtin_amdgcn_mfma_f32_16x16x32_bf16(av, bf, accI[g], 0, 0, 0);
            }
        }
        const float keepA = (ep[t * BB + am] != 0) ? 0.0f : 1.0f;

        // ---- acquire h_{t-1}: fast (XCD L2) with bounded retries, else mirror ----
        short8 a[KS_H];
        float hprev_raw[4];
        if (t == 0) {
            const float* hrow = h0 + (size_t)am * HH;
            #pragma unroll
            for (int ks = 0; ks < KS_H; ks++) {
                int k0 = ks * 32 + k0a;
                #pragma unroll
                for (int j = 0; j < 8; j++) a[ks][j] = f2bf(hrow[k0 + j] * keepA);
            }
            #pragma unroll
            for (int j = 0; j < 4; j++)
                hprev_raw[j] = h0[(size_t)(bg * 16 + rbase + j) * HH + col];
        } else {
            const unsigned int tgt = (unsigned int)(t - 1 + TAG_OFF);
            const size_t roff = ((size_t)((t & 1) ^ 1)) * BB * HH;
            const unsigned int* fb  = fx + roff + (size_t)am * HH + k0a;
            const unsigned int* fq0 = fx + roff + (size_t)(bg * 16 + rbase) * HH + col;
            const unsigned int* fq2 = fx + roff + (size_t)(bg * 16 + rbase + 2) * HH + col;
            const unsigned int* mb  = mx + roff + (size_t)am * HH + k0a;
            const unsigned int* mq0 = mx + roff + (size_t)(bg * 16 + rbase) * HH + col;
            const unsigned int* mq2 = mx + roff + (size_t)(bg * 16 + rbase + 2) * HH + col;
            uintx4 u0[KS_H], u1[KS_H];
            unsigned int hp[4];
            bool need_mirror = false;
            int tries = 0;
            for (;;) {   // FAST: sc0 loads through the (shared, if grouping holds) L2
                #pragma unroll
                for (int ks = 0; ks < KS_H; ks++) {
                    asm volatile("global_load_dwordx4 %0, %2, off offset:%c3 sc0\n\t"
                                 "global_load_dwordx4 %1, %2, off offset:%c4 sc0"
                                 : "=&v"(u0[ks]), "=&v"(u1[ks])
                                 : "v"(fb), "n"(ks * 128), "n"(ks * 128 + 16)
                                 : "memory");
                }
                asm volatile("global_load_dword %0, %2, off sc0\n\t"
                             "global_load_dword %1, %2, off offset:2048 sc0"
                             : "=&v"(hp[0]), "=&v"(hp[1]) : "v"(fq0) : "memory");
                asm volatile("global_load_dword %0, %2, off sc0\n\t"
                             "global_load_dword %1, %2, off offset:2048 sc0"
                             : "=&v"(hp[2]), "=&v"(hp[3]) : "v"(fq2) : "memory");
                asm volatile("s_waitcnt vmcnt(0)" ::: "memory");
                __builtin_amdgcn_sched_barrier(0);
                unsigned int bad = 0;
                #pragma unroll
                for (int ks = 0; ks < KS_H; ks++) {
                    #pragma unroll
                    for (int j = 0; j < 4; j++) {
                        bad |= (u0[ks][j] ^ tgt) & 0xffffu;
                        bad |= (u1[ks][j] ^ tgt) & 0xffffu;
                    }
                }
                #pragma unroll
                for (int j = 0; j < 4; j++) bad |= (hp[j] ^ tgt) & 0xffffu;
                if (__all(bad == 0)) break;
                if (++tries >= FAST_TRIES) { need_mirror = true; break; }
                __builtin_amdgcn_s_sleep(1);
            }
            if (need_mirror) {
                for (;;) {   // MIRROR: sc0sc1 (LLC) — the r2/r3-proven mechanism
                    #pragma unroll
                    for (int ks = 0; ks < KS_H; ks++) {
                        asm volatile("global_load_dwordx4 %0, %2, off offset:%c3 sc0 sc1\n\t"
                                     "global_load_dwordx4 %1, %2, off offset:%c4 sc0 sc1"
                                     : "=&v"(u0[ks]), "=&v"(u1[ks])
                                     : "v"(mb), "n"(ks * 128), "n"(ks * 128 + 16)
                                     : "memory");
                    }
                    asm volatile("global_load_dword %0, %2, off sc0 sc1\n\t"
                                 "global_load_dword %1, %2, off offset:2048 sc0 sc1"
                                 : "=&v"(hp[0]), "=&v"(hp[1]) : "v"(mq0) : "memory");
                    asm volatile("global_load_dword %0, %2, off sc0 sc1\n\t"
                                 "global_load_dword %1, %2, off offset:2048 sc0 sc1"
                                 : "=&v"(hp[2]), "=&v"(hp[3]) : "v"(mq2) : "memory");
                    asm volatile("s_waitcnt vmcnt(0)" ::: "memory");
                    __builtin_amdgcn_sched_barrier(0);
                    unsigned int bad = 0;
                    #pragma unroll
                    for (int ks = 0; ks < KS_H; ks++) {
                        #pragma unroll
                        for (int j = 0; j < 4; j++) {
                            bad |= (u0[ks][j] ^ tgt) & 0xffffu;
                            bad |= (u1[ks][j] ^ tgt) & 0xffffu;
                        }
                    }
                    #pragma unroll
                    for (int j = 0; j < 4; j++) bad |= (hp[j] ^ tgt) & 0xffffu;
                    if (__all(bad == 0)) break;
                    __builtin_amdgcn_s_sleep(2);
                }
            }
            #pragma unroll
            for (int ks = 0; ks < KS_H; ks++) {
                union { short8 s; uintx4 u; } cv;
                cv.u[0] = (u0[ks][1] & 0xffff0000u) | (u0[ks][0] >> 16);
                cv.u[1] = (u0[ks][3] & 0xffff0000u) | (u0[ks][2] >> 16);
                cv.u[2] = (u1[ks][1] & 0xffff0000u) | (u1[ks][0] >> 16);
                cv.u[3] = (u1[ks][3] & 0xffff0000u) | (u1[ks][2] >> 16);
                a[ks] = cv.s;
            }
            if (keepA == 0.0f) {
                #pragma unroll
                for (int ks = 0; ks < KS_H; ks++) a[ks] = (short8)0;
            }
            #pragma unroll
            for (int j = 0; j < 4; j++) hprev_raw[j] = bf2f_hi(hp[j]);
        }

        // ---- h-side GEMM ----
        #pragma unroll
        for (int ks = 0; ks < KS_H; ks++) {
            #pragma unroll
            for (int g = 0; g < 3; g++) {
                short8 bf = *(const short8*)&ldsw[(size_t)((w * 3 + g) * KS_TOT + KS_X + ks) * 512 + lane * 8];
                accH[g] = __builtin_amdgcn_mfma_f32_16x16x32_bf16(a[ks], bf, accH[g], 0, 0, 0);
            }
        }

        // ---- epilogue: gates; dual-store tagged words (fast plain + mirror sc1) ----
        const size_t woff = ((size_t)(t & 1)) * BB * HH;
        float hnv[4];
        #pragma unroll
        for (int j = 0; j < 4; j++) {
            const int mo = bg * 16 + rbase + j;
            const float keep = (ep[t * BB + mo] != 0) ? 0.0f : 1.0f;
            const float hprev = hprev_raw[j] * keep;
            const float r = sigm(accI[0][j] + accH[0][j] + br0);
            const float z = sigm(accI[1][j] + accH[1][j] + bz0);
            const float n = tanhf(accI[2][j] + bin + r * (accH[2][j] + bhn));
            hnv[j] = (1.0f - z) * n + z * hprev;
            if (t < TT - 1) {
                unsigned int word = (((unsigned int)(unsigned short)f2bf(hnv[j])) << 16)
                                  | (unsigned int)((t + TAG_OFF) & 0xffff);
                unsigned int* pf = fx + woff + (size_t)mo * HH + col;
                unsigned int* pm = mx + woff + (size_t)mo * HH + col;
                asm volatile("global_store_dword %0, %1, off"
                             :: "v"(pf), "v"(word) : "memory");
                asm volatile("global_store_dword %0, %1, off sc0 sc1"
                             :: "v"(pm), "v"(word) : "memory");
            }
        }

        // ---- out stores: plain cached, off the critical path ----
        #pragma unroll
        for (int j = 0; j < 4; j++) {
            const int mo = bg * 16 + rbase + j;
            out[((size_t)t * BB + mo) * HH + col] = hnv[j];
            if (t == TT - 1) out[(size_t)TT * BB * HH + (size_t)mo * HH + col] = hnv[j];
        }
    }
}

extern "C" void kernel_launch(void* const* d_in, const int* in_sizes, int n_in,
                              void* d_out, int out_size, void* d_ws, size_t ws_size,
                              hipStream_t stream) {
    const float* x   = (const float*)d_in[0];
    const float* h0  = (const float*)d_in[1];
    const int*   ep  = (const int*)d_in[2];
    const float* wih = (const float*)d_in[3];
    const float* whh = (const float*)d_in[4];
    const float* bih = (const float*)d_in[5];
    const float* bhh = (const float*)d_in[6];
    float* out = (float*)d_out;

    unsigned int* fx   = (unsigned int*)d_ws;                          // 1 MB fast ping-pong
    unsigned int* mx   = (unsigned int*)((char*)d_ws + 1048576);       // 1 MB mirror ping-pong
    unsigned int* xcnt = (unsigned int*)((char*)d_ws + 2097152);       // 8 rank counters

    hipLaunchKernelGGL(clear_ws, dim3(1), dim3(64), 0, stream, xcnt);
    hipLaunchKernelGGL(gru_persistent, dim3(256), dim3(128), 0, stream,
                       x, h0, ep, wih, whh, bih, bhh, out, fx, mx, xcnt);
}